// Round 2
// baseline (36016.284 us; speedup 1.0000x reference)
//
#include <hip/hip_runtime.h>
#include <math.h>

// FullRankRNN: h' = h + (0.05*noise + 0.2*inp@wi_full) + 0.2*(-h + tanh(h)@wrec^T)
//              out_t = tanh(h') @ wo_full
//
// Round-2 design: 2 blocks per batch (256 blocks x 512 threads, 1 block/CU).
// Block owns 256 output columns; ALL its weights live on-chip:
//   - 144 k-rows in LDS (147 KB, 4-row interleaved for ds_read_b128)
//   - 368 k-rows in 184 pinned VGPRs/thread (asm pin defeats remat — Round-1
//     showed VGPR_Count=104: the compiler re-streamed "register" weights from L2)
// Per step the partner's 256 r-values arrive via a double-buffered global
// xbuf + agent-scope release/acquire flag. Pairing bid<->bid^8 keeps partners
// on one XCD (perf heuristic only). Deadlock-safe under partial residency:
// any co-resident pair completes and frees its CUs.

#define Bn 128
#define Tn 1000
#define In 4
#define Hn 512
#define On 2
#define ALPHA 0.2f
#define NSTD 0.05f

#define HALF 256     // columns per block
#define LR 72        // LDS k-rows per phase (x2 phases = 144)
#define RR 92        // register k-rows per thread per phase (x2 hh, x2 phases)
// per phase: LR + 2*RR = 256 k-rows  ✓ full coverage

__global__ void prep_kernel(const float* __restrict__ wi, const float* __restrict__ si,
                            const float* __restrict__ wrec, const float* __restrict__ wo,
                            const float* __restrict__ so,
                            float* __restrict__ wrecT, float* __restrict__ wi_full,
                            float* __restrict__ wo_full, float* __restrict__ out,
                            int* __restrict__ flags) {
    int idx = blockIdx.x * blockDim.x + threadIdx.x;
    int stride = gridDim.x * blockDim.x;
    // wrecT[k][j] = wrec[j][k] (coalesced writes; 1 MB reads L2-absorbed)
    for (int e = idx; e < Hn * Hn; e += stride) {
        int j = e & (Hn - 1);
        int k = e >> 9;
        wrecT[k * Hn + j] = wrec[j * Hn + k];
    }
    if (idx < In * Hn) wi_full[idx] = wi[idx] * si[idx >> 9];
    if (idx < Hn * On) wo_full[idx] = wo[idx] * so[idx & 1];
    // out accumulated via atomicAdd by two blocks -> zero it (re-poisoned 0xAA
    // before every timed launch, so this must run every launch)
    for (int e = idx; e < Bn * Tn * On; e += stride) out[e] = 0.f;
    if (idx < Bn * 2) flags[idx] = 0;
}

__global__ __launch_bounds__(512, 2) void rnn_kernel(
    const float* __restrict__ input, const float* __restrict__ noise,
    const float* __restrict__ h0, const float* __restrict__ wrecT,
    const float* __restrict__ wi_full, const float* __restrict__ wo_full,
    float* xbuf, int* flags, float* __restrict__ out) {
    extern __shared__ float lds[];
    float* wl0  = lds;                      // [LR/4][256][4] phase-0 weights
    float* wl1  = lds + LR * HALF;          // [LR/4][256][4] phase-1 weights
    float* r_s  = lds + 2 * LR * HALF;      // [512] full r vector
    float* pacc = r_s + Hn;                 // [256] hh1 partials
    float* red  = pacc + HALF;              // [8]   cross-wave out partials

    const int tid  = threadIdx.x;
    const int c    = tid & (HALF - 1);      // column within block
    const int hh   = tid >> 8;              // k-range sub-half (0/1)

    // bid -> (batch, half) with partner = bid^8 (same XCD slot under round-robin)
    const int bid  = blockIdx.x;
    const int g    = bid & 7;
    const int s    = bid >> 3;
    const int b    = g * 16 + (s >> 1);
    const int half = s & 1;

    const int base0 = half * HALF;          // own k-range (r computed locally)
    const int base1 = (1 - half) * HALF;    // partner k-range
    const int gc    = half * HALF + c;      // global column of this thread

    // ---- stage LDS weights: rows [baseP, baseP+LR), 4-row interleaved ----
    for (int e = tid; e < LR * HALF; e += 512) {
        int lr = e >> 8;
        int cc = e & 255;
        int dst = (lr >> 2) * 1024 + cc * 4 + (lr & 3);
        wl0[dst] = wrecT[(base0 + lr) * Hn + half * HALF + cc];
        wl1[dst] = wrecT[(base1 + lr) * Hn + half * HALF + cc];
    }

    // ---- register weights: rows [baseP+LR+hh*RR, +RR), pinned ----
    float w0[RR], w1[RR];
#pragma unroll
    for (int i = 0; i < RR; ++i)
        w0[i] = wrecT[(base0 + LR + hh * RR + i) * Hn + gc];
#pragma unroll
    for (int i = 0; i < RR; ++i)
        w1[i] = wrecT[(base1 + LR + hh * RR + i) * Hn + gc];
#pragma unroll
    for (int i = 0; i < RR; ++i) asm volatile("" : "+v"(w0[i]));
#pragma unroll
    for (int i = 0; i < RR; ++i) asm volatile("" : "+v"(w1[i]));

    const float wi0 = wi_full[0 * Hn + gc], wi1 = wi_full[1 * Hn + gc],
                wi2 = wi_full[2 * Hn + gc], wi3 = wi_full[3 * Hn + gc];
    const float wo0 = wo_full[gc * On + 0], wo1 = wo_full[gc * On + 1];

    float h = h0[gc];                        // live state only on hh==0
    r_s[tid] = tanhf(h0[tid]);               // t=0: both blocks build FULL r locally
    __syncthreads();

    const float* noise_p = noise + (size_t)b * Tn * Hn + half * HALF + c;
    const float* inp_p   = input + (size_t)b * Tn * In;
    float*       out_p   = out   + (size_t)b * Tn * On;

    float*       xb_mine = xbuf + (size_t)((b * 2 + half) * 2) * HALF;
    const float* xb_part = xbuf + (size_t)((b * 2 + (1 - half)) * 2) * HALF;
    int* flag_mine    = flags + b * 2 + half;
    int* flag_partner = flags + b * 2 + (1 - half);

    const float4* r4    = (const float4*)r_s;
    const float4* wl4_0 = (const float4*)wl0;
    const float4* wl4_1 = (const float4*)wl1;
    const int rB0 = base0 >> 2, rB1 = base1 >> 2;

    for (int t = 0; t < Tn; ++t) {
        // early-issue global loads (hh0 only; wave-uniform branch)
        float nz = 0.f;
        float4 inp = {0.f, 0.f, 0.f, 0.f};
        if (hh == 0) {
            nz  = noise_p[(size_t)t * Hn];
            inp = *(const float4*)(inp_p + t * In);
        }

        float a0 = 0.f, a1 = 0.f, a2 = 0.f, a3 = 0.f;

        // ---- phase 0: own k-half (r_s[base0..] valid from previous step) ----
#pragma unroll
        for (int m = 0; m < LR / 8; ++m) {           // 9 groups of 4 LDS rows
            float4 wv = wl4_0[(hh * 9 + m) * 256 + c];
            float4 rv = r4[rB0 + hh * 9 + m];
            a0 = fmaf(rv.x, wv.x, a0);
            a1 = fmaf(rv.y, wv.y, a1);
            a2 = fmaf(rv.z, wv.z, a2);
            a3 = fmaf(rv.w, wv.w, a3);
        }
#pragma unroll
        for (int m = 0; m < RR / 4; ++m) {           // 23 groups of 4 reg rows
            float4 rv = r4[rB0 + (LR >> 2) + hh * (RR >> 2) + m];
            a0 = fmaf(rv.x, w0[4 * m + 0], a0);
            a1 = fmaf(rv.y, w0[4 * m + 1], a1);
            a2 = fmaf(rv.z, w0[4 * m + 2], a2);
            a3 = fmaf(rv.w, w0[4 * m + 3], a3);
        }

        // ---- wait for partner r (state t), stage into r_s[base1..] ----
        if (t > 0) {
            if (tid == 0) {
                while (__hip_atomic_load(flag_partner, __ATOMIC_ACQUIRE,
                                         __HIP_MEMORY_SCOPE_AGENT) < t) {
                    __builtin_amdgcn_s_sleep(1);
                }
            }
            __syncthreads();                         // acquire (L1/L2 inv) done
            if (tid < HALF)
                r_s[base1 + tid] = __hip_atomic_load(
                    &xb_part[(t & 1) * HALF + tid], __ATOMIC_RELAXED,
                    __HIP_MEMORY_SCOPE_AGENT);
            __syncthreads();
        }

        // ---- phase 1: partner k-half ----
#pragma unroll
        for (int m = 0; m < LR / 8; ++m) {
            float4 wv = wl4_1[(hh * 9 + m) * 256 + c];
            float4 rv = r4[rB1 + hh * 9 + m];
            a0 = fmaf(rv.x, wv.x, a0);
            a1 = fmaf(rv.y, wv.y, a1);
            a2 = fmaf(rv.z, wv.z, a2);
            a3 = fmaf(rv.w, wv.w, a3);
        }
#pragma unroll
        for (int m = 0; m < RR / 4; ++m) {
            float4 rv = r4[rB1 + (LR >> 2) + hh * (RR >> 2) + m];
            a0 = fmaf(rv.x, w1[4 * m + 0], a0);
            a1 = fmaf(rv.y, w1[4 * m + 1], a1);
            a2 = fmaf(rv.z, w1[4 * m + 2], a2);
            a3 = fmaf(rv.w, w1[4 * m + 3], a3);
        }

        // ---- combine hh halves, update h, publish r ----
        float acc = (a0 + a1) + (a2 + a3);
        if (hh == 1) pacc[c] = acc;
        __syncthreads();
        if (hh == 0) {
            float total = acc + pacc[c];
            float drive = NSTD * nz +
                          ALPHA * (inp.x * wi0 + inp.y * wi1 +
                                   inp.z * wi2 + inp.w * wi3);
            h = h + drive + ALPHA * (total - h);
            float rn = tanhf(h);
            r_s[base0 + c] = rn;                         // local publish
            xb_mine[((t + 1) & 1) * HALF + c] = rn;      // remote publish (slot t+1)
            // partial output over this block's 256 columns
            float p0 = rn * wo0, p1 = rn * wo1;
#pragma unroll
            for (int off = 32; off > 0; off >>= 1) {
                p0 += __shfl_down(p0, off, 64);
                p1 += __shfl_down(p1, off, 64);
            }
            if ((tid & 63) == 0) {
                red[(tid >> 6) * 2 + 0] = p0;
                red[(tid >> 6) * 2 + 1] = p1;
            }
        }
        __syncthreads();                                 // xbuf stores drained
        if (tid == 0) {
            __threadfence();                             // device-scope: L2 wb
            __hip_atomic_store(flag_mine, t + 1, __ATOMIC_RELEASE,
                               __HIP_MEMORY_SCOPE_AGENT);
            float s0 = red[0] + red[2] + red[4] + red[6];
            float s1 = red[1] + red[3] + red[5] + red[7];
            atomicAdd(&out_p[t * On + 0], s0);
            atomicAdd(&out_p[t * On + 1], s1);
        }
    }
}

extern "C" void kernel_launch(void* const* d_in, const int* in_sizes, int n_in,
                              void* d_out, int out_size, void* d_ws, size_t ws_size,
                              hipStream_t stream) {
    const float* input = (const float*)d_in[0];
    const float* noise = (const float*)d_in[1];
    const float* wi    = (const float*)d_in[2];
    const float* si    = (const float*)d_in[3];
    const float* wrec  = (const float*)d_in[4];
    const float* wo    = (const float*)d_in[5];
    const float* so    = (const float*)d_in[6];
    const float* h0    = (const float*)d_in[7];
    float* out = (float*)d_out;

    // ws: wrecT 1MB | wi_full 8KB | wo_full 4KB | xbuf 512KB | flags 1KB
    float* wrecT   = (float*)d_ws;
    float* wi_full = wrecT + Hn * Hn;
    float* wo_full = wi_full + In * Hn;
    float* xbuf    = wo_full + Hn * On;
    int*   flags   = (int*)(xbuf + Bn * 2 * 2 * HALF);

    prep_kernel<<<512, 512, 0, stream>>>(wi, si, wrec, wo, so, wrecT, wi_full,
                                         wo_full, out, flags);

    const size_t lds_bytes =
        (size_t)(2 * LR * HALF + Hn + HALF + 8) * sizeof(float);  // 150,560 B
    hipFuncSetAttribute((const void*)rnn_kernel,
                        hipFuncAttributeMaxDynamicSharedMemorySize, (int)lds_bytes);
    rnn_kernel<<<2 * Bn, 512, lds_bytes, stream>>>(input, noise, h0, wrecT,
                                                   wi_full, wo_full, xbuf, flags,
                                                   out);
}